// Round 1
// baseline (2104.595 us; speedup 1.0000x reference)
//
#include <hip/hip_runtime.h>
#include <hip/hip_bf16.h>
#include <cstdint>
#include <cstddef>

#define VOCAB 50001
#define EMB 64
#define HID 128
#define G4  512   // 4*HID
#define TAGS 32
#define BATCH 256
#define SEQ 512

__device__ __forceinline__ float fsig(float x) {
  return 1.0f / (1.0f + __expf(-x));
}
__device__ __forceinline__ float ftanh(float x) {
  // stable: x->+inf => 1, x->-inf => -1 (no inf/inf NaN)
  float e = __expf(2.0f * x);
  return 1.0f - 2.0f / (e + 1.0f);
}

// ---------------------------------------------------------------------------
// Kernel A: gate tables  G[v, j] = sum_k E[v,k] * Wk[k,j] + b[j]   (bf16 out)
// grid (ceil(VOCAB/64), 512/64, 2), block 256
// ---------------------------------------------------------------------------
__global__ __launch_bounds__(256)
void gtab_kernel(const float* __restrict__ E,
                 const float* __restrict__ Wk_f, const float* __restrict__ b_f,
                 const float* __restrict__ Wk_b, const float* __restrict__ b_b,
                 __hip_bfloat16* __restrict__ G_f, __hip_bfloat16* __restrict__ G_b) {
  const int dir = blockIdx.z;
  const float* __restrict__ Wk   = dir ? Wk_b : Wk_f;
  const float* __restrict__ bias = dir ? b_b  : b_f;
  __hip_bfloat16* __restrict__ G = dir ? G_b  : G_f;

  __shared__ float Es[64][65];
  __shared__ float Ws[64][65];

  const int m0 = blockIdx.x * 64;
  const int n0 = blockIdx.y * 64;
  const int tid = threadIdx.x;

  for (int i = tid; i < 64 * 64; i += 256) {
    int r = i >> 6, c = i & 63;
    int row = m0 + r;
    Es[r][c] = (row < VOCAB) ? E[row * EMB + c] : 0.0f;
    Ws[r][c] = Wk[r * G4 + n0 + c];
  }
  __syncthreads();

  const int tx = tid & 15, ty = tid >> 4;
  float acc[4][4] = {{0.f}};
  #pragma unroll 8
  for (int k = 0; k < 64; ++k) {
    float a0 = Es[ty*4+0][k], a1 = Es[ty*4+1][k], a2 = Es[ty*4+2][k], a3 = Es[ty*4+3][k];
    float w0 = Ws[k][tx*4+0], w1 = Ws[k][tx*4+1], w2 = Ws[k][tx*4+2], w3 = Ws[k][tx*4+3];
    acc[0][0] += a0*w0; acc[0][1] += a0*w1; acc[0][2] += a0*w2; acc[0][3] += a0*w3;
    acc[1][0] += a1*w0; acc[1][1] += a1*w1; acc[1][2] += a1*w2; acc[1][3] += a1*w3;
    acc[2][0] += a2*w0; acc[2][1] += a2*w1; acc[2][2] += a2*w2; acc[2][3] += a2*w3;
    acc[3][0] += a3*w0; acc[3][1] += a3*w1; acc[3][2] += a3*w2; acc[3][3] += a3*w3;
  }
  float bv[4];
  #pragma unroll
  for (int jj = 0; jj < 4; ++jj) bv[jj] = bias[n0 + tx*4 + jj];
  #pragma unroll
  for (int i = 0; i < 4; ++i) {
    int row = m0 + ty*4 + i;
    if (row < VOCAB) {
      #pragma unroll
      for (int jj = 0; jj < 4; ++jj)
        G[(size_t)row * G4 + n0 + tx*4 + jj] = __float2bfloat16(acc[i][jj] + bv[jj]);
    }
  }
}

// ---------------------------------------------------------------------------
// Kernel B: LSTM recurrence, one block per (batch, dir), 512 threads.
// Thread j owns gate column j: wr[k] = Wr[k, j] in registers.
// Fuses the logits projection: thread j = kk*16 + p contributes the partial
// dot over h[p*8 .. p*8+8) to tag kk, reduced via 16-lane shfl_xor.
// ---------------------------------------------------------------------------
__global__ __launch_bounds__(512, 2)
void lstm_kernel(const int* __restrict__ tokens,
                 const __hip_bfloat16* __restrict__ G_f,
                 const __hip_bfloat16* __restrict__ G_b,
                 const float* __restrict__ Wr_f,
                 const float* __restrict__ Wr_b,
                 const float* __restrict__ Wd,
                 float* __restrict__ logit_f,
                 float* __restrict__ logit_b) {
  const int b   = blockIdx.x;
  const int dir = blockIdx.y;
  const __hip_bfloat16* __restrict__ G = dir ? G_b : G_f;
  const float* __restrict__ Wr = dir ? Wr_b : Wr_f;
  float* __restrict__ lg = dir ? logit_b : logit_f;

  const int j = threadIdx.x;

  __shared__ __align__(16) float h_lds[HID];
  __shared__ float z_lds[G4];
  __shared__ int tok_lds[SEQ];

  float wr[HID];
  #pragma unroll
  for (int k = 0; k < HID; ++k) wr[k] = Wr[k * G4 + j];

  const int kk = j >> 4;   // tag index 0..31
  const int p  = j & 15;   // partial index 0..15  (16 contiguous lanes per tag)
  float wd[8];
  #pragma unroll
  for (int u = 0; u < 8; ++u) wd[u] = Wd[(dir * HID + p * 8 + u) * TAGS + kk];

  tok_lds[j] = tokens[(size_t)b * SEQ + j];
  if (j < HID) h_lds[j] = 0.0f;
  float c = 0.0f;
  __syncthreads();

  for (int s = 0; s < SEQ; ++s) {
    const int t = dir ? (SEQ - 1 - s) : s;
    const int tok = tok_lds[t];
    const float gv = __bfloat162float(G[(size_t)tok * G4 + j]);

    const float4* h4 = (const float4*)h_lds;
    float z0 = 0.f, z1 = 0.f, z2 = 0.f, z3 = 0.f;
    #pragma unroll
    for (int k = 0; k < HID / 4; ++k) {
      float4 hv = h4[k];
      z0 += wr[4*k+0] * hv.x;
      z1 += wr[4*k+1] * hv.y;
      z2 += wr[4*k+2] * hv.z;
      z3 += wr[4*k+3] * hv.w;
    }
    z_lds[j] = gv + ((z0 + z1) + (z2 + z3));
    __syncthreads();

    if (j < HID) {
      float zi = z_lds[j];
      float zf = z_lds[HID + j];
      float zg = z_lds[2 * HID + j];
      float zo = z_lds[3 * HID + j];
      c = fsig(zf) * c + fsig(zi) * ftanh(zg);
      h_lds[j] = fsig(zo) * ftanh(c);
    }
    __syncthreads();

    // fused logits partial: tag kk, h slice [p*8, p*8+8)
    float4 ha = h4[p * 2], hb = h4[p * 2 + 1];
    float sacc = wd[0]*ha.x + wd[1]*ha.y + wd[2]*ha.z + wd[3]*ha.w
               + wd[4]*hb.x + wd[5]*hb.y + wd[6]*hb.z + wd[7]*hb.w;
    sacc += __shfl_xor(sacc, 1);
    sacc += __shfl_xor(sacc, 2);
    sacc += __shfl_xor(sacc, 4);
    sacc += __shfl_xor(sacc, 8);
    if (p == 0) lg[((size_t)b * SEQ + t) * TAGS + kk] = sacc;
  }
}

// ---------------------------------------------------------------------------
// Kernel C: CRF log-likelihood. One wave per batch element.
// lane = jh*32 + k : tag k, j-half jh (each half does 16 of the 32 prev-tags).
// ---------------------------------------------------------------------------
__global__ __launch_bounds__(64)
void crf_kernel(const float* __restrict__ logit_f,
                const float* __restrict__ logit_b,
                const float* __restrict__ bd,
                const float* __restrict__ trans,
                const int* __restrict__ labels,
                float* __restrict__ out) {
  const int b = blockIdx.x;
  const int lane = threadIdx.x;
  const int k  = lane & 31;
  const int jh = lane >> 5;

  __shared__ float tr[TAGS * TAGS];
  __shared__ float alpha[TAGS];

  for (int i = lane; i < TAGS * TAGS; i += 64) tr[i] = trans[i];

  const float bdv = bd[k];
  const size_t base0 = (size_t)b * SEQ * TAGS;

  if (lane < TAGS)
    alpha[k] = logit_f[base0 + k] + logit_b[base0 + k] + bdv;
  __syncthreads();

  float nxt = 0.f;
  if (lane < TAGS)
    nxt = logit_f[base0 + TAGS + k] + logit_b[base0 + TAGS + k];

  for (int t = 1; t < SEQ; ++t) {
    float cur = nxt;
    if (t + 1 < SEQ && lane < TAGS) {
      size_t idx = base0 + (size_t)(t + 1) * TAGS + k;
      nxt = logit_f[idx] + logit_b[idx];
    }

    float m = -1e30f;
    #pragma unroll
    for (int i = 0; i < 16; ++i) {
      int jt = jh * 16 + i;
      m = fmaxf(m, alpha[jt] + tr[jt * TAGS + k]);
    }
    float ssum = 0.f;
    #pragma unroll
    for (int i = 0; i < 16; ++i) {
      int jt = jh * 16 + i;
      ssum += __expf(alpha[jt] + tr[jt * TAGS + k] - m);
    }
    // combine the two j-halves (lane <-> lane^32)
    float m2 = __shfl_xor(m, 32);
    float s2 = __shfl_xor(ssum, 32);
    float mm = fmaxf(m, m2);
    float stot = ssum * __expf(m - mm) + s2 * __expf(m2 - mm);
    float anew = mm + __logf(stot) + cur + bdv;
    __syncthreads();
    if (lane < TAGS) alpha[k] = anew;
    __syncthreads();
  }

  // log_norm = logsumexp(alpha)
  float av = (lane < TAGS) ? alpha[k] : -1e30f;
  float m = av;
  #pragma unroll
  for (int off = 1; off <= 16; off <<= 1) m = fmaxf(m, __shfl_xor(m, off));
  float ex = (lane < TAGS) ? __expf(av - m) : 0.0f;
  float s = ex;
  #pragma unroll
  for (int off = 1; off <= 32; off <<= 1) s += __shfl_xor(s, off);

  // unary + binary
  const int* lab = labels + (size_t)b * SEQ;
  float uacc = 0.f, bacc = 0.f;
  for (int t = lane; t < SEQ; t += 64) {
    int l0 = lab[t];
    size_t idx = base0 + (size_t)t * TAGS + l0;
    uacc += logit_f[idx] + logit_b[idx] + bd[l0];
    if (t + 1 < SEQ) bacc += tr[l0 * TAGS + lab[t + 1]];
  }
  float red = uacc + bacc;
  #pragma unroll
  for (int off = 1; off <= 32; off <<= 1) red += __shfl_xor(red, off);

  if (lane == 0) out[b] = red - (m + __logf(s));
}

// ---------------------------------------------------------------------------
// Kernel D: copy transition matrix to the second output slot.
// ---------------------------------------------------------------------------
__global__ void copy_trans_kernel(const float* __restrict__ trans,
                                  float* __restrict__ out) {
  int i = blockIdx.x * blockDim.x + threadIdx.x;
  if (i < TAGS * TAGS) out[i] = trans[i];
}

extern "C" void kernel_launch(void* const* d_in, const int* in_sizes, int n_in,
                              void* d_out, int out_size, void* d_ws, size_t ws_size,
                              hipStream_t stream) {
  const int*   inputs = (const int*)  d_in[0];
  const int*   labels = (const int*)  d_in[1];
  const float* E      = (const float*)d_in[2];
  const float* Wk_f   = (const float*)d_in[3];
  const float* Wr_f   = (const float*)d_in[4];
  const float* b_f    = (const float*)d_in[5];
  const float* Wk_b   = (const float*)d_in[6];
  const float* Wr_b   = (const float*)d_in[7];
  const float* b_b    = (const float*)d_in[8];
  const float* Wd     = (const float*)d_in[9];
  const float* bd     = (const float*)d_in[10];
  const float* trans  = (const float*)d_in[11];
  float* out = (float*)d_out;

  char* ws = (char*)d_ws;
  const size_t G_BYTES = (size_t)VOCAB * G4 * sizeof(__hip_bfloat16); // 51,201,024
  __hip_bfloat16* G_f = (__hip_bfloat16*)ws;
  __hip_bfloat16* G_b = (__hip_bfloat16*)(ws + G_BYTES);
  float* logit_f = (float*)(ws + 2 * G_BYTES);
  float* logit_b = (float*)(ws + 2 * G_BYTES + (size_t)BATCH * SEQ * TAGS * sizeof(float));

  dim3 ggrid((VOCAB + 63) / 64, G4 / 64, 2);
  gtab_kernel<<<ggrid, 256, 0, stream>>>(E, Wk_f, b_f, Wk_b, b_b, G_f, G_b);

  lstm_kernel<<<dim3(BATCH, 2), 512, 0, stream>>>(inputs, G_f, G_b, Wr_f, Wr_b,
                                                  Wd, logit_f, logit_b);

  crf_kernel<<<BATCH, 64, 0, stream>>>(logit_f, logit_b, bd, trans, labels, out);

  copy_trans_kernel<<<(TAGS * TAGS + 255) / 256, 256, 0, stream>>>(trans, out + BATCH);
}

// Round 3
// 956.665 us; speedup vs baseline: 2.1999x; 2.1999x over previous
//
#include <hip/hip_runtime.h>
#include <hip/hip_bf16.h>
#include <cstdint>
#include <cstddef>

#define VOCAB 50001
#define EMB 64
#define HID 128
#define G4  512   // 4*HID
#define TAGS 32
#define BATCH 256
#define SEQ 512

typedef _Float16 f16;
typedef _Float16 f16x2 __attribute__((ext_vector_type(2)));

__device__ __forceinline__ f16x2 bc_h2(unsigned int x) {
  return __builtin_bit_cast(f16x2, x);
}

#if __has_builtin(__builtin_amdgcn_fdot2)
__device__ __forceinline__ float FDOT2(f16x2 a, f16x2 b, float c) {
  return __builtin_amdgcn_fdot2(a, b, c, false);
}
#else
__device__ __forceinline__ float FDOT2(f16x2 a, f16x2 b, float c) {
  return c + (float)a.x * (float)b.x + (float)a.y * (float)b.y;
}
#endif

__device__ __forceinline__ float fsig(float x) {
  return 1.0f / (1.0f + __expf(-x));
}
__device__ __forceinline__ float ftanh(float x) {
  float e = __expf(2.0f * x);
  return 1.0f - 2.0f / (e + 1.0f);
}

// ---------------------------------------------------------------------------
// Kernel A: gate tables  G[v, j] = sum_k E[v,k] * Wk[k,j] + b[j]   (f16 out)
// ---------------------------------------------------------------------------
__global__ __launch_bounds__(256)
void gtab_kernel(const float* __restrict__ E,
                 const float* __restrict__ Wk_f, const float* __restrict__ b_f,
                 const float* __restrict__ Wk_b, const float* __restrict__ b_b,
                 f16* __restrict__ G_f, f16* __restrict__ G_b) {
  const int dir = blockIdx.z;
  const float* __restrict__ Wk   = dir ? Wk_b : Wk_f;
  const float* __restrict__ bias = dir ? b_b  : b_f;
  f16* __restrict__ G = dir ? G_b : G_f;

  __shared__ float Es[64][65];
  __shared__ float Ws[64][65];

  const int m0 = blockIdx.x * 64;
  const int n0 = blockIdx.y * 64;
  const int tid = threadIdx.x;

  for (int i = tid; i < 64 * 64; i += 256) {
    int r = i >> 6, c = i & 63;
    int row = m0 + r;
    Es[r][c] = (row < VOCAB) ? E[row * EMB + c] : 0.0f;
    Ws[r][c] = Wk[r * G4 + n0 + c];
  }
  __syncthreads();

  const int tx = tid & 15, ty = tid >> 4;
  float acc[4][4] = {{0.f}};
  #pragma unroll 8
  for (int k = 0; k < 64; ++k) {
    float a0 = Es[ty*4+0][k], a1 = Es[ty*4+1][k], a2 = Es[ty*4+2][k], a3 = Es[ty*4+3][k];
    float w0 = Ws[k][tx*4+0], w1 = Ws[k][tx*4+1], w2 = Ws[k][tx*4+2], w3 = Ws[k][tx*4+3];
    acc[0][0] += a0*w0; acc[0][1] += a0*w1; acc[0][2] += a0*w2; acc[0][3] += a0*w3;
    acc[1][0] += a1*w0; acc[1][1] += a1*w1; acc[1][2] += a1*w2; acc[1][3] += a1*w3;
    acc[2][0] += a2*w0; acc[2][1] += a2*w1; acc[2][2] += a2*w2; acc[2][3] += a2*w3;
    acc[3][0] += a3*w0; acc[3][1] += a3*w1; acc[3][2] += a3*w2; acc[3][3] += a3*w3;
  }
  float bv[4];
  #pragma unroll
  for (int jj = 0; jj < 4; ++jj) bv[jj] = bias[n0 + tx*4 + jj];
  #pragma unroll
  for (int i = 0; i < 4; ++i) {
    int row = m0 + ty*4 + i;
    if (row < VOCAB) {
      #pragma unroll
      for (int jj = 0; jj < 4; ++jj)
        G[(size_t)row * G4 + n0 + tx*4 + jj] = (f16)(acc[i][jj] + bv[jj]);
    }
  }
}

// ---------------------------------------------------------------------------
// Kernel B: LSTM recurrence. One block per (batch, dir), 256 threads.
// Thread j owns gate columns 2j and 2j+1 with Wr packed as f16 pairs along k
// (128 VGPRs). h broadcast from LDS as f16 (16 ds_read_b128 per thread-step).
// h (f16) written to global; logits deferred to a separate GEMM.
// ---------------------------------------------------------------------------
__global__ __launch_bounds__(256, 2)
void lstm_kernel(const int* __restrict__ tokens,
                 const f16* __restrict__ G_f,
                 const f16* __restrict__ G_b,
                 const float* __restrict__ Wr_f,
                 const float* __restrict__ Wr_b,
                 f16* __restrict__ h_out) {
  const int b   = blockIdx.x;
  const int dir = blockIdx.y;
  const f16* __restrict__ G = dir ? G_b : G_f;
  const float* __restrict__ Wr = dir ? Wr_b : Wr_f;
  const int j = threadIdx.x;

  __shared__ __align__(16) f16 h_lds[HID];
  __shared__ __align__(16) float z_lds[G4];
  __shared__ int tok_lds[SEQ];

  // Pack Wr columns (2j, 2j+1), k-pairs (2m, 2m+1) -> f16x2
  f16x2 w0[64], w1[64];
  #pragma unroll
  for (int m = 0; m < 64; ++m) {
    float2 a = *(const float2*)(Wr + (size_t)(2*m)   * G4 + 2*j);
    float2 c = *(const float2*)(Wr + (size_t)(2*m+1) * G4 + 2*j);
    f16x2 v0; v0.x = (f16)a.x; v0.y = (f16)c.x;
    f16x2 v1; v1.x = (f16)a.y; v1.y = (f16)c.y;
    w0[m] = v0; w1[m] = v1;
  }

  tok_lds[j]       = tokens[(size_t)b * SEQ + j];
  tok_lds[j + 256] = tokens[(size_t)b * SEQ + j + 256];
  if (j < 64) ((unsigned int*)h_lds)[j] = 0u;
  float c = 0.0f;
  __syncthreads();

  // Prefetch G for step 0
  int t0 = dir ? (SEQ - 1) : 0;
  f16x2 gcur = *(const f16x2*)(G + (size_t)tok_lds[t0] * G4 + 2*j);

  for (int s = 0; s < SEQ; ++s) {
    const int t = dir ? (SEQ - 1 - s) : s;
    // issue next-step G load early (independent of h)
    const int sn = (s + 1 < SEQ) ? (s + 1) : s;
    const int tn = dir ? (SEQ - 1 - sn) : sn;
    f16x2 gnext = *(const f16x2*)(G + (size_t)tok_lds[tn] * G4 + 2*j);

    float z0 = 0.f, z1 = 0.f;
    const uint4* hv = (const uint4*)h_lds;
    #pragma unroll
    for (int r = 0; r < 16; ++r) {
      uint4 u = hv[r];
      z0 = FDOT2(w0[4*r+0], bc_h2(u.x), z0);  z1 = FDOT2(w1[4*r+0], bc_h2(u.x), z1);
      z0 = FDOT2(w0[4*r+1], bc_h2(u.y), z0);  z1 = FDOT2(w1[4*r+1], bc_h2(u.y), z1);
      z0 = FDOT2(w0[4*r+2], bc_h2(u.z), z0);  z1 = FDOT2(w1[4*r+2], bc_h2(u.z), z1);
      z0 = FDOT2(w0[4*r+3], bc_h2(u.w), z0);  z1 = FDOT2(w1[4*r+3], bc_h2(u.w), z1);
    }
    float2 zz; zz.x = z0 + (float)gcur.x; zz.y = z1 + (float)gcur.y;
    *(float2*)(z_lds + 2*j) = zz;
    __syncthreads();

    if (j < HID) {
      float zi = z_lds[j];
      float zf = z_lds[HID + j];
      float zg = z_lds[2 * HID + j];
      float zo = z_lds[3 * HID + j];
      c = fsig(zf) * c + fsig(zi) * ftanh(zg);
      float h = fsig(zo) * ftanh(c);
      h_lds[j] = (f16)h;
      h_out[((size_t)b * SEQ + t) * (2 * HID) + dir * HID + j] = (f16)h;
    }
    __syncthreads();
    gcur = gnext;
  }
}

// ---------------------------------------------------------------------------
// Kernel C: logits GEMM  L[row, k] = sum_u H[row,u] * Wd[u,k] + bd[k]
// row = b*SEQ + t (131072 rows), u < 256, k < 32.
// Block = 256 threads, 128 rows/block. Thread: col k = tid&31, row-group tid>>5.
// Wd column held in 128 packed-f16 registers; H rows broadcast-read.
// ---------------------------------------------------------------------------
#define LROWS 128
__global__ __launch_bounds__(256, 2)
void logits_kernel(const f16* __restrict__ H, const float* __restrict__ Wd,
                   const float* __restrict__ bd, float* __restrict__ L) {
  const int k  = threadIdx.x & 31;
  const int rg = threadIdx.x >> 5;
  const size_t base = (size_t)blockIdx.x * LROWS;

  f16x2 wd[128];
  #pragma unroll
  for (int m = 0; m < 128; ++m) {
    f16x2 v; v.x = (f16)Wd[(2*m) * TAGS + k]; v.y = (f16)Wd[(2*m+1) * TAGS + k];
    wd[m] = v;
  }
  const float bdv = bd[k];

  for (int i = 0; i < LROWS / 8; ++i) {
    size_t row = base + (size_t)i * 8 + rg;
    const uint4* hp = (const uint4*)(H + row * (2 * HID));
    float acc = 0.f;
    #pragma unroll
    for (int r = 0; r < 16; ++r) {
      uint4 u = hp[r];
      acc = FDOT2(wd[4*r+0], bc_h2(u.x), acc);
      acc = FDOT2(wd[4*r+1], bc_h2(u.y), acc);
      acc = FDOT2(wd[4*r+2], bc_h2(u.z), acc);
      acc = FDOT2(wd[4*r+3], bc_h2(u.w), acc);
    }
    L[row * TAGS + k] = acc + bdv;
  }
}

// ---------------------------------------------------------------------------
// Kernel D: CRF log-likelihood. One wave per batch element.
// L already includes bd. lane = jh*32 + k.
// ---------------------------------------------------------------------------
__global__ __launch_bounds__(64)
void crf_kernel(const float* __restrict__ L,
                const float* __restrict__ trans,
                const int* __restrict__ labels,
                float* __restrict__ out) {
  const int b = blockIdx.x;
  const int lane = threadIdx.x;
  const int k  = lane & 31;
  const int jh = lane >> 5;

  __shared__ float tr[TAGS * TAGS];
  __shared__ float alpha[TAGS];

  for (int i = lane; i < TAGS * TAGS; i += 64) tr[i] = trans[i];

  const size_t base0 = (size_t)b * SEQ * TAGS;

  if (lane < TAGS) alpha[k] = L[base0 + k];
  __syncthreads();

  float nxt = 0.f;
  if (lane < TAGS) nxt = L[base0 + TAGS + k];

  for (int t = 1; t < SEQ; ++t) {
    float cur = nxt;
    if (t + 1 < SEQ && lane < TAGS)
      nxt = L[base0 + (size_t)(t + 1) * TAGS + k];

    float m = -1e30f;
    #pragma unroll
    for (int i = 0; i < 16; ++i) {
      int jt = jh * 16 + i;
      m = fmaxf(m, alpha[jt] + tr[jt * TAGS + k]);
    }
    float ssum = 0.f;
    #pragma unroll
    for (int i = 0; i < 16; ++i) {
      int jt = jh * 16 + i;
      ssum += __expf(alpha[jt] + tr[jt * TAGS + k] - m);
    }
    float m2 = __shfl_xor(m, 32);
    float s2 = __shfl_xor(ssum, 32);
    float mm = fmaxf(m, m2);
    float stot = ssum * __expf(m - mm) + s2 * __expf(m2 - mm);
    float anew = mm + __logf(stot) + cur;
    __syncthreads();
    if (lane < TAGS) alpha[k] = anew;
    __syncthreads();
  }

  float av = (lane < TAGS) ? alpha[k] : -1e30f;
  float m = av;
  #pragma unroll
  for (int off = 1; off <= 16; off <<= 1) m = fmaxf(m, __shfl_xor(m, off));
  float ex = (lane < TAGS) ? __expf(av - m) : 0.0f;
  float s = ex;
  #pragma unroll
  for (int off = 1; off <= 32; off <<= 1) s += __shfl_xor(s, off);

  const int* lab = labels + (size_t)b * SEQ;
  float uacc = 0.f, bacc = 0.f;
  for (int t = lane; t < SEQ; t += 64) {
    int l0 = lab[t];
    uacc += L[base0 + (size_t)t * TAGS + l0];
    if (t + 1 < SEQ) bacc += tr[l0 * TAGS + lab[t + 1]];
  }
  float red = uacc + bacc;
  #pragma unroll
  for (int off = 1; off <= 32; off <<= 1) red += __shfl_xor(red, off);

  if (lane == 0) out[b] = red - (m + __logf(s));
}

// ---------------------------------------------------------------------------
// Kernel E: copy transition matrix to the second output slot.
// ---------------------------------------------------------------------------
__global__ void copy_trans_kernel(const float* __restrict__ trans,
                                  float* __restrict__ out) {
  int i = blockIdx.x * blockDim.x + threadIdx.x;
  if (i < TAGS * TAGS) out[i] = trans[i];
}

extern "C" void kernel_launch(void* const* d_in, const int* in_sizes, int n_in,
                              void* d_out, int out_size, void* d_ws, size_t ws_size,
                              hipStream_t stream) {
  const int*   inputs = (const int*)  d_in[0];
  const int*   labels = (const int*)  d_in[1];
  const float* E      = (const float*)d_in[2];
  const float* Wk_f   = (const float*)d_in[3];
  const float* Wr_f   = (const float*)d_in[4];
  const float* b_f    = (const float*)d_in[5];
  const float* Wk_b   = (const float*)d_in[6];
  const float* Wr_b   = (const float*)d_in[7];
  const float* b_b    = (const float*)d_in[8];
  const float* Wd     = (const float*)d_in[9];
  const float* bd     = (const float*)d_in[10];
  const float* trans  = (const float*)d_in[11];
  float* out = (float*)d_out;

  char* ws = (char*)d_ws;
  const size_t G_ELEMS = (size_t)VOCAB * G4;            // 25,600,512 f16 each dir
  f16* G_f = (f16*)ws;
  f16* G_b = G_f + G_ELEMS;
  f16* H   = (f16*)(ws + 2 * G_ELEMS * sizeof(f16));    // 131072 x 256 f16
  float* L = (float*)ws;  // reuses G region AFTER lstm is done (stream-ordered)

  dim3 ggrid((VOCAB + 63) / 64, G4 / 64, 2);
  gtab_kernel<<<ggrid, 256, 0, stream>>>(E, Wk_f, b_f, Wk_b, b_b, G_f, G_b);

  lstm_kernel<<<dim3(BATCH, 2), 256, 0, stream>>>(inputs, G_f, G_b, Wr_f, Wr_b, H);

  logits_kernel<<<(BATCH * SEQ) / LROWS, 256, 0, stream>>>(H, Wd, bd, L);

  crf_kernel<<<BATCH, 64, 0, stream>>>(L, trans, labels, out);

  copy_trans_kernel<<<(TAGS * TAGS + 255) / 256, 256, 0, stream>>>(trans, out + BATCH);
}

// Round 4
// 862.111 us; speedup vs baseline: 2.4412x; 1.1097x over previous
//
#include <hip/hip_runtime.h>
#include <hip/hip_bf16.h>
#include <cstdint>
#include <cstddef>

#define VOCAB 50001
#define EMB 64
#define HID 128
#define G4  512   // 4*HID
#define TAGS 32
#define BATCH 256
#define SEQ 512

typedef _Float16 f16;
typedef _Float16 f16x2 __attribute__((ext_vector_type(2)));

__device__ __forceinline__ f16x2 bc_h2(unsigned int x) {
  return __builtin_bit_cast(f16x2, x);
}

#if __has_builtin(__builtin_amdgcn_fdot2)
__device__ __forceinline__ float FDOT2(f16x2 a, f16x2 b, float c) {
  return __builtin_amdgcn_fdot2(a, b, c, false);
}
#else
__device__ __forceinline__ float FDOT2(f16x2 a, f16x2 b, float c) {
  return c + (float)a.x * (float)b.x + (float)a.y * (float)b.y;
}
#endif

__device__ __forceinline__ float fsig(float x) {
  return 1.0f / (1.0f + __expf(-x));
}
__device__ __forceinline__ float ftanh(float x) {
  float e = __expf(2.0f * x);
  return 1.0f - 2.0f / (e + 1.0f);
}

// ---------------------------------------------------------------------------
// Kernel A: gate tables  G[v, j] = sum_k E[v,k] * Wk[k,j] + b[j]   (f16 out)
// f16x2 staging + v_dot2_f32_f16 inner loop (2 MAC/instr).
// ---------------------------------------------------------------------------
__global__ __launch_bounds__(256)
void gtab_kernel(const float* __restrict__ E,
                 const float* __restrict__ Wk_f, const float* __restrict__ b_f,
                 const float* __restrict__ Wk_b, const float* __restrict__ b_b,
                 f16* __restrict__ G_f, f16* __restrict__ G_b) {
  const int dir = blockIdx.z;
  const float* __restrict__ Wk   = dir ? Wk_b : Wk_f;
  const float* __restrict__ bias = dir ? b_b  : b_f;
  f16* __restrict__ G = dir ? G_b : G_f;

  __shared__ f16x2 Eh[64][33];   // [row][kk] packed k-pairs, +1 pad
  __shared__ f16x2 Wh[64][33];   // [col][kk]

  const int m0 = blockIdx.x * 64;
  const int n0 = blockIdx.y * 64;
  const int tid = threadIdx.x;

  #pragma unroll
  for (int s = 0; s < 8; ++s) {
    int idx = tid + s * 256;          // 0..2047
    int r = idx >> 5, kk = idx & 31;  // 64 rows x 32 kk
    int row = m0 + r;
    float2 ev;
    if (row < VOCAB) ev = *(const float2*)(E + (size_t)row * EMB + 2 * kk);
    else { ev.x = 0.f; ev.y = 0.f; }
    f16x2 v; v.x = (f16)ev.x; v.y = (f16)ev.y;
    Eh[r][kk] = v;
  }
  #pragma unroll
  for (int s = 0; s < 8; ++s) {
    int idx = tid + s * 256;
    int kk = idx >> 6, cc = idx & 63; // 32 kk x 64 cols
    float a  = Wk[(size_t)(2 * kk)     * G4 + n0 + cc];
    float b2 = Wk[(size_t)(2 * kk + 1) * G4 + n0 + cc];
    f16x2 v; v.x = (f16)a; v.y = (f16)b2;
    Wh[cc][kk] = v;
  }
  __syncthreads();

  const int tx = tid & 15, ty = tid >> 4;
  float acc[4][4] = {{0.f}};
  #pragma unroll 4
  for (int kk = 0; kk < 32; ++kk) {
    f16x2 a0 = Eh[ty*4+0][kk], a1 = Eh[ty*4+1][kk], a2 = Eh[ty*4+2][kk], a3 = Eh[ty*4+3][kk];
    f16x2 w0 = Wh[tx*4+0][kk], w1 = Wh[tx*4+1][kk], w2 = Wh[tx*4+2][kk], w3 = Wh[tx*4+3][kk];
    acc[0][0] = FDOT2(a0, w0, acc[0][0]); acc[0][1] = FDOT2(a0, w1, acc[0][1]);
    acc[0][2] = FDOT2(a0, w2, acc[0][2]); acc[0][3] = FDOT2(a0, w3, acc[0][3]);
    acc[1][0] = FDOT2(a1, w0, acc[1][0]); acc[1][1] = FDOT2(a1, w1, acc[1][1]);
    acc[1][2] = FDOT2(a1, w2, acc[1][2]); acc[1][3] = FDOT2(a1, w3, acc[1][3]);
    acc[2][0] = FDOT2(a2, w0, acc[2][0]); acc[2][1] = FDOT2(a2, w1, acc[2][1]);
    acc[2][2] = FDOT2(a2, w2, acc[2][2]); acc[2][3] = FDOT2(a2, w3, acc[2][3]);
    acc[3][0] = FDOT2(a3, w0, acc[3][0]); acc[3][1] = FDOT2(a3, w1, acc[3][1]);
    acc[3][2] = FDOT2(a3, w2, acc[3][2]); acc[3][3] = FDOT2(a3, w3, acc[3][3]);
  }
  float bv[4];
  #pragma unroll
  for (int jj = 0; jj < 4; ++jj) bv[jj] = bias[n0 + tx*4 + jj];
  #pragma unroll
  for (int i = 0; i < 4; ++i) {
    int row = m0 + ty*4 + i;
    if (row < VOCAB) {
      #pragma unroll
      for (int jj = 0; jj < 4; ++jj)
        G[(size_t)row * G4 + n0 + tx*4 + jj] = (f16)(acc[i][jj] + bv[jj]);
    }
  }
}

// ---------------------------------------------------------------------------
// Kernel B: LSTM recurrence, TWO batches per block. 256 blocks (128 pairs x
// 2 dirs), 256 threads. Thread j owns gate columns 2j,2j+1 (f16x2 weights in
// 128 VGPRs), computes z for both batches (4 independent dot chains for ILP).
// Gate phase: all 256 threads active (thread t -> batch t>>7, elem t&127),
// balancing transcendentals across all 4 SIMDs. Barriers amortized 2x.
// ---------------------------------------------------------------------------
__global__ __launch_bounds__(256, 1)
void lstm_kernel(const int* __restrict__ tokens,
                 const f16* __restrict__ G_f,
                 const f16* __restrict__ G_b,
                 const float* __restrict__ Wr_f,
                 const float* __restrict__ Wr_b,
                 f16* __restrict__ h_out) {
  const int p   = blockIdx.x;         // batch pair 0..127
  const int dir = blockIdx.y;
  const int b0 = 2 * p, b1 = 2 * p + 1;
  const f16* __restrict__ G = dir ? G_b : G_f;
  const float* __restrict__ Wr = dir ? Wr_b : Wr_f;
  const int j = threadIdx.x;

  __shared__ __align__(16) f16 h_lds[2][HID];
  __shared__ __align__(16) float z_lds[2][G4];
  __shared__ int tok_lds[2][SEQ];

  // Pack Wr columns (2j, 2j+1), k-pairs (2m, 2m+1) -> f16x2
  f16x2 w0[64], w1[64];
  #pragma unroll
  for (int m = 0; m < 64; ++m) {
    float2 a = *(const float2*)(Wr + (size_t)(2*m)   * G4 + 2*j);
    float2 c = *(const float2*)(Wr + (size_t)(2*m+1) * G4 + 2*j);
    f16x2 v0; v0.x = (f16)a.x; v0.y = (f16)c.x;
    f16x2 v1; v1.x = (f16)a.y; v1.y = (f16)c.y;
    w0[m] = v0; w1[m] = v1;
  }

  #pragma unroll
  for (int s = 0; s < 2; ++s) {
    tok_lds[0][j + 256*s] = tokens[(size_t)b0 * SEQ + 256*s + j];
    tok_lds[1][j + 256*s] = tokens[(size_t)b1 * SEQ + 256*s + j];
  }
  if (j < 128) ((unsigned int*)h_lds)[j] = 0u;   // 2*128 f16 = 128 dwords
  float c = 0.0f;   // cell state for (batch j>>7, elem j&127)
  __syncthreads();

  const int t0 = dir ? (SEQ - 1) : 0;
  f16x2 g0 = *(const f16x2*)(G + (size_t)tok_lds[0][t0] * G4 + 2*j);
  f16x2 g1 = *(const f16x2*)(G + (size_t)tok_lds[1][t0] * G4 + 2*j);

  for (int s = 0; s < SEQ; ++s) {
    const int t = dir ? (SEQ - 1 - s) : s;
    const int sn = (s + 1 < SEQ) ? (s + 1) : s;
    const int tn = dir ? (SEQ - 1 - sn) : sn;
    f16x2 gn0 = *(const f16x2*)(G + (size_t)tok_lds[0][tn] * G4 + 2*j);
    f16x2 gn1 = *(const f16x2*)(G + (size_t)tok_lds[1][tn] * G4 + 2*j);

    float z00 = 0.f, z01 = 0.f, z10 = 0.f, z11 = 0.f;
    const uint4* hv0 = (const uint4*)h_lds[0];
    const uint4* hv1 = (const uint4*)h_lds[1];
    #pragma unroll
    for (int r = 0; r < 16; ++r) {
      uint4 u0 = hv0[r];
      uint4 u1 = hv1[r];
      z00 = FDOT2(w0[4*r+0], bc_h2(u0.x), z00);  z01 = FDOT2(w1[4*r+0], bc_h2(u0.x), z01);
      z00 = FDOT2(w0[4*r+1], bc_h2(u0.y), z00);  z01 = FDOT2(w1[4*r+1], bc_h2(u0.y), z01);
      z00 = FDOT2(w0[4*r+2], bc_h2(u0.z), z00);  z01 = FDOT2(w1[4*r+2], bc_h2(u0.z), z01);
      z00 = FDOT2(w0[4*r+3], bc_h2(u0.w), z00);  z01 = FDOT2(w1[4*r+3], bc_h2(u0.w), z01);
      z10 = FDOT2(w0[4*r+0], bc_h2(u1.x), z10);  z11 = FDOT2(w1[4*r+0], bc_h2(u1.x), z11);
      z10 = FDOT2(w0[4*r+1], bc_h2(u1.y), z10);  z11 = FDOT2(w1[4*r+1], bc_h2(u1.y), z11);
      z10 = FDOT2(w0[4*r+2], bc_h2(u1.z), z10);  z11 = FDOT2(w1[4*r+2], bc_h2(u1.z), z11);
      z10 = FDOT2(w0[4*r+3], bc_h2(u1.w), z10);  z11 = FDOT2(w1[4*r+3], bc_h2(u1.w), z11);
    }
    float2 za; za.x = z00 + (float)g0.x; za.y = z01 + (float)g0.y;
    float2 zb; zb.x = z10 + (float)g1.x; zb.y = z11 + (float)g1.y;
    *(float2*)(&z_lds[0][2*j]) = za;
    *(float2*)(&z_lds[1][2*j]) = zb;
    __syncthreads();

    {
      const int bb = j >> 7;
      const int e  = j & 127;
      float zi = z_lds[bb][e];
      float zf = z_lds[bb][HID + e];
      float zg = z_lds[bb][2 * HID + e];
      float zo = z_lds[bb][3 * HID + e];
      c = fsig(zf) * c + fsig(zi) * ftanh(zg);
      float h = fsig(zo) * ftanh(c);
      h_lds[bb][e] = (f16)h;
      h_out[((size_t)(2*p + bb) * SEQ + t) * (2 * HID) + dir * HID + e] = (f16)h;
    }
    __syncthreads();
    g0 = gn0; g1 = gn1;
  }
}

// ---------------------------------------------------------------------------
// Kernel C: logits GEMM  L[row, k] = sum_u H[row,u] * Wd[u,k] + bd[k]
// H tile (128 rows x 256 f16 = 32KB) staged in LDS once per block, then
// broadcast-read (kills the 32x redundant global row reads).
// ---------------------------------------------------------------------------
#define LROWS 128
__global__ __launch_bounds__(256, 2)
void logits_kernel(const f16* __restrict__ H, const float* __restrict__ Wd,
                   const float* __restrict__ bd, float* __restrict__ L) {
  __shared__ uint4 hs[LROWS * 16];   // 32 KB
  const int k  = threadIdx.x & 31;
  const int rg = threadIdx.x >> 5;
  const size_t base = (size_t)blockIdx.x * LROWS;

  f16x2 wd[128];
  #pragma unroll
  for (int m = 0; m < 128; ++m) {
    f16x2 v; v.x = (f16)Wd[(2*m) * TAGS + k]; v.y = (f16)Wd[(2*m+1) * TAGS + k];
    wd[m] = v;
  }
  const float bdv = bd[k];

  const uint4* hg = (const uint4*)(H + base * (2 * HID));  // 2048 uint4
  #pragma unroll
  for (int s = 0; s < 8; ++s) hs[threadIdx.x + 256 * s] = hg[threadIdx.x + 256 * s];
  __syncthreads();

  for (int i = 0; i < 16; ++i) {
    int row = i * 8 + rg;
    const uint4* hp = &hs[row * 16];
    float acc = 0.f;
    #pragma unroll
    for (int r = 0; r < 16; ++r) {
      uint4 u = hp[r];
      acc = FDOT2(wd[4*r+0], bc_h2(u.x), acc);
      acc = FDOT2(wd[4*r+1], bc_h2(u.y), acc);
      acc = FDOT2(wd[4*r+2], bc_h2(u.z), acc);
      acc = FDOT2(wd[4*r+3], bc_h2(u.w), acc);
    }
    L[(base + row) * TAGS + k] = acc + bdv;
  }
}

// ---------------------------------------------------------------------------
// Kernel D: CRF log-likelihood. One wave per batch element.
// ---------------------------------------------------------------------------
__global__ __launch_bounds__(64)
void crf_kernel(const float* __restrict__ L,
                const float* __restrict__ trans,
                const int* __restrict__ labels,
                float* __restrict__ out) {
  const int b = blockIdx.x;
  const int lane = threadIdx.x;
  const int k  = lane & 31;
  const int jh = lane >> 5;

  __shared__ float tr[TAGS * TAGS];
  __shared__ float alpha[TAGS];

  for (int i = lane; i < TAGS * TAGS; i += 64) tr[i] = trans[i];

  const size_t base0 = (size_t)b * SEQ * TAGS;

  if (lane < TAGS) alpha[k] = L[base0 + k];
  __syncthreads();

  float nxt = 0.f;
  if (lane < TAGS) nxt = L[base0 + TAGS + k];

  for (int t = 1; t < SEQ; ++t) {
    float cur = nxt;
    if (t + 1 < SEQ && lane < TAGS)
      nxt = L[base0 + (size_t)(t + 1) * TAGS + k];

    float m = -1e30f;
    #pragma unroll
    for (int i = 0; i < 16; ++i) {
      int jt = jh * 16 + i;
      m = fmaxf(m, alpha[jt] + tr[jt * TAGS + k]);
    }
    float ssum = 0.f;
    #pragma unroll
    for (int i = 0; i < 16; ++i) {
      int jt = jh * 16 + i;
      ssum += __expf(alpha[jt] + tr[jt * TAGS + k] - m);
    }
    float m2 = __shfl_xor(m, 32);
    float s2 = __shfl_xor(ssum, 32);
    float mm = fmaxf(m, m2);
    float stot = ssum * __expf(m - mm) + s2 * __expf(m2 - mm);
    float anew = mm + __logf(stot) + cur;
    __syncthreads();
    if (lane < TAGS) alpha[k] = anew;
    __syncthreads();
  }

  float av = (lane < TAGS) ? alpha[k] : -1e30f;
  float m = av;
  #pragma unroll
  for (int off = 1; off <= 16; off <<= 1) m = fmaxf(m, __shfl_xor(m, off));
  float ex = (lane < TAGS) ? __expf(av - m) : 0.0f;
  float s = ex;
  #pragma unroll
  for (int off = 1; off <= 32; off <<= 1) s += __shfl_xor(s, off);

  const int* lab = labels + (size_t)b * SEQ;
  float uacc = 0.f, bacc = 0.f;
  for (int t = lane; t < SEQ; t += 64) {
    int l0 = lab[t];
    uacc += L[base0 + (size_t)t * TAGS + l0];
    if (t + 1 < SEQ) bacc += tr[l0 * TAGS + lab[t + 1]];
  }
  float red = uacc + bacc;
  #pragma unroll
  for (int off = 1; off <= 32; off <<= 1) red += __shfl_xor(red, off);

  if (lane == 0) out[b] = red - (m + __logf(s));
}

// ---------------------------------------------------------------------------
// Kernel E: copy transition matrix to the second output slot.
// ---------------------------------------------------------------------------
__global__ void copy_trans_kernel(const float* __restrict__ trans,
                                  float* __restrict__ out) {
  int i = blockIdx.x * blockDim.x + threadIdx.x;
  if (i < TAGS * TAGS) out[i] = trans[i];
}

extern "C" void kernel_launch(void* const* d_in, const int* in_sizes, int n_in,
                              void* d_out, int out_size, void* d_ws, size_t ws_size,
                              hipStream_t stream) {
  const int*   inputs = (const int*)  d_in[0];
  const int*   labels = (const int*)  d_in[1];
  const float* E      = (const float*)d_in[2];
  const float* Wk_f   = (const float*)d_in[3];
  const float* Wr_f   = (const float*)d_in[4];
  const float* b_f    = (const float*)d_in[5];
  const float* Wk_b   = (const float*)d_in[6];
  const float* Wr_b   = (const float*)d_in[7];
  const float* b_b    = (const float*)d_in[8];
  const float* Wd     = (const float*)d_in[9];
  const float* bd     = (const float*)d_in[10];
  const float* trans  = (const float*)d_in[11];
  float* out = (float*)d_out;

  char* ws = (char*)d_ws;
  const size_t G_ELEMS = (size_t)VOCAB * G4;            // 25,600,512 f16 each dir
  f16* G_f = (f16*)ws;
  f16* G_b = G_f + G_ELEMS;
  f16* H   = (f16*)(ws + 2 * G_ELEMS * sizeof(f16));    // 131072 x 256 f16
  float* L = (float*)ws;  // reuses G region AFTER lstm is done (stream-ordered)

  dim3 ggrid((VOCAB + 63) / 64, G4 / 64, 2);
  gtab_kernel<<<ggrid, 256, 0, stream>>>(E, Wk_f, b_f, Wk_b, b_b, G_f, G_b);

  lstm_kernel<<<dim3(BATCH / 2, 2), 256, 0, stream>>>(inputs, G_f, G_b, Wr_f, Wr_b, H);

  logits_kernel<<<(BATCH * SEQ) / LROWS, 256, 0, stream>>>(H, Wd, bd, L);

  crf_kernel<<<BATCH, 64, 0, stream>>>(L, trans, labels, out);

  copy_trans_kernel<<<(TAGS * TAGS + 255) / 256, 256, 0, stream>>>(trans, out + BATCH);
}